// Round 6
// baseline (304.652 us; speedup 1.0000x reference)
//
#include <hip/hip_runtime.h>
#include <math.h>

// AFM forward, round 6: split each sample across TWO waves (r4/r5 showed the
// kernel is latency/serial-bound, not pipe-bound: halving LDS traffic was
// neutral while both pipes sit <50% busy). Wave-half wh in {0,1} of a sample
// does tiles t = wh + 2k (12 tiles instead of 24) -> per-wave serial chain
// halves; staging gathers also split across the wave pair. Per-tile math is
// bit-identical to r5 (bf16 rows in LDS, 32x32x16 MFMA, K=16 exact, v_perm
// packs, exp2 with pre-scaled proj_h). Cross-wave (aw,Z) combine via LDS.

#define BB 8192
#define FF 39
#define PP 741
#define NT 24                 // total 32-pair tiles per sample
#define NTW 12                // tiles per wave (2 waves per sample)
#define RBYTES 48             // bf16 row stride: 32B data + 16B pad
#define SBYTES (FF * RBYTES)  // 1872 B per sample

typedef short bf16x8 __attribute__((ext_vector_type(8)));
typedef float f32x4  __attribute__((ext_vector_type(4)));
typedef float f32x16 __attribute__((ext_vector_type(16)));

// pack two fp32 -> dword of two bf16 (truncation), single v_perm_b32
static __device__ __forceinline__ unsigned pack2(float lo, float hi) {
    return __builtin_amdgcn_perm(__builtin_bit_cast(unsigned, hi),
                                 __builtin_bit_cast(unsigned, lo),
                                 0x07060302u);
}
static __device__ __forceinline__ float up_lo(unsigned d) {
    return __builtin_bit_cast(float, d << 16);
}
static __device__ __forceinline__ float up_hi(unsigned d) {
    return __builtin_bit_cast(float, d & 0xFFFF0000u);
}

__global__ __launch_bounds__(256, 8)
void afm_kernel(const int*   __restrict__ fidx,
                const float* __restrict__ fval,
                const float* __restrict__ fow,
                const float* __restrict__ emb,
                const float* __restrict__ bias,
                const float* __restrict__ aw_,   // [E=16][A=16] row-major
                const float* __restrict__ ab_,   // [16]
                const float* __restrict__ ph_,   // [16]
                const float* __restrict__ pp_,   // [16]
                float*       __restrict__ out)
{
    __shared__ __align__(16) unsigned char s_emb[2 * SBYTES];  // 3744 B
    __shared__ unsigned s_pij[NT * 32];                        // 3072 B
    __shared__ float s_red[4][2];                              // per-wave aw,z

    const int tid  = threadIdx.x;
    const int wid  = tid >> 6;
    const int lane = tid & 63;
    const int n    = lane & 31;      // pair slot within tile
    const int h    = lane >> 5;      // e-half / k-half
    const int ws   = wid >> 1;       // sample slot in block (0/1)
    const int wh   = wid & 1;        // wave-half within sample
    const int smp  = blockIdx.x * 2 + ws;

    // ---- pair table (block-shared): (i*48)<<16 | (j*48) byte offsets ----
    if (tid < FF - 1) {
        int i = tid;
        int base = (i * (2 * FF - i - 1)) >> 1;
        for (int j = i + 1; j < FF; ++j)
            s_pij[base++] = ((unsigned)(i * RBYTES) << 16) | (unsigned)(j * RBYTES);
    } else if (tid == FF - 1) {
        for (int e = PP; e < NT * 32; ++e) s_pij[e] = 0u;  // dead slots
    }

    // ---- per-sample: indices/values (both waves), first-order (even wave) --
    int ixr = 0; float vr = 0.f, fo = 0.f;
    if (lane < FF) {
        ixr = fidx[smp * FF + lane];
        vr  = fval[smp * FF + lane];
    }
    if (wh == 0) {
        if (lane < FF) fo = fow[ixr] * vr;
        #pragma unroll
        for (int m = 1; m < 64; m <<= 1) fo += __shfl_xor(fo, m);
    }

    // ---- stage scaled rows as bf16: 78 half-row tasks over the 2 waves ----
    unsigned char* my = s_emb + ws * SBYTES;
    {
        int u = lane + 64 * wh;
        if (u < FF * 2) {
            int row = u >> 1, hh = u & 1;
            int   ix = __shfl(ixr, row);
            float v  = __shfl(vr,  row);
            const float4* src = (const float4*)emb + (size_t)ix * 4 + hh * 2;
            float4 e0 = src[0], e1 = src[1];
            uint4 d = make_uint4(pack2(e0.x * v, e0.y * v),
                                 pack2(e0.z * v, e0.w * v),
                                 pack2(e1.x * v, e1.y * v),
                                 pack2(e1.z * v, e1.w * v));
            *(uint4*)(my + row * RBYTES + hh * 16) = d;
        }
    }

    // ---- constant fragments ----
    const float LOG2E = 1.44269504088896f;
    f32x4 h_lo = ((const f32x4*)ph_)[h];        // a = 4h + reg      (regs 0-3)
    f32x4 h_hi = ((const f32x4*)ph_)[h + 2];    // a = 8 + 4h + reg  (regs 4-7)
    #pragma unroll
    for (int r = 0; r < 4; ++r) { h_lo[r] *= LOG2E; h_hi[r] *= LOG2E; }

    f32x16 cinit;                               // bias rows a<16, zero above
    {
        const f32x4 ab_lo = ((const f32x4*)ab_)[h];
        const f32x4 ab_hi = ((const f32x4*)ab_)[h + 2];
        cinit[0] = ab_lo[0]; cinit[1] = ab_lo[1];
        cinit[2] = ab_lo[2]; cinit[3] = ab_lo[3];
        cinit[4] = ab_hi[0]; cinit[5] = ab_hi[1];
        cinit[6] = ab_hi[2]; cinit[7] = ab_hi[3];
        #pragma unroll
        for (int r = 8; r < 16; ++r) cinit[r] = 0.f;
    }

    bf16x8 wfrag;                               // A = W^T, rows m>=16 zero
    {
        float t0 = 0.f, t1 = 0.f, t2 = 0.f, t3 = 0.f,
              t4 = 0.f, t5 = 0.f, t6 = 0.f, t7 = 0.f;
        if (n < 16) {
            const float* base = aw_ + (8 * h) * 16 + n;  // W[k=8h+j][m=n]
            t0 = base[0];   t1 = base[16];  t2 = base[32];  t3 = base[48];
            t4 = base[64];  t5 = base[80];  t6 = base[96];  t7 = base[112];
        }
        union { unsigned i[4]; bf16x8 v; } u;
        u.i[0] = pack2(t0, t1); u.i[1] = pack2(t2, t3);
        u.i[2] = pack2(t4, t5); u.i[3] = pack2(t6, t7);
        wfrag = u.v;
    }

    __syncthreads();   // staging (cross-wave within sample) + s_pij

    // ---- main loop: this wave's 12 tiles (t = wh + 2k) ----
    const unsigned char* bpre = my + h * 16;    // this lane's e-half
    const unsigned* pijp = s_pij + wh * 32 + n; // stride 64 dwords per k
    float p0=0.f,p1=0.f,p2=0.f,p3=0.f,p4=0.f,p5=0.f,p6=0.f,p7=0.f;
    float z = 0.f;
    // last global tile (t=23) is held by wh==1, k==11; valid pairs: n < 5
    const int lastk = (wh == 1) ? (NTW - 1) : NTW;

    #pragma unroll 4
    for (int k = 0; k < NTW; ++k) {
        unsigned pk = pijp[k * 64];
        uint4 di = *(const uint4*)(bpre + (pk >> 16));
        uint4 dj = *(const uint4*)(bpre + (pk & 0xFFFFu));
        float m0 = up_lo(di.x) * up_lo(dj.x);
        float m1 = up_hi(di.x) * up_hi(dj.x);
        float m2 = up_lo(di.y) * up_lo(dj.y);
        float m3 = up_hi(di.y) * up_hi(dj.y);
        float m4 = up_lo(di.z) * up_lo(dj.z);
        float m5 = up_hi(di.z) * up_hi(dj.z);
        float m6 = up_lo(di.w) * up_lo(dj.w);
        float m7 = up_hi(di.w) * up_hi(dj.w);
        union { unsigned i[4]; bf16x8 v; } u;
        u.i[0] = pack2(m0, m1); u.i[1] = pack2(m2, m3);
        u.i[2] = pack2(m4, m5); u.i[3] = pack2(m6, m7);
        f32x16 d = __builtin_amdgcn_mfma_f32_32x32x16_bf16(wfrag, u.v,
                                                           cinit, 0, 0, 0);
        float s = fmaf(fmaxf(d[0], 0.f), h_lo[0],
                  fmaf(fmaxf(d[1], 0.f), h_lo[1],
                  fmaf(fmaxf(d[2], 0.f), h_lo[2],
                  fmaf(fmaxf(d[3], 0.f), h_lo[3],
                  fmaf(fmaxf(d[4], 0.f), h_hi[0],
                  fmaf(fmaxf(d[5], 0.f), h_hi[1],
                  fmaf(fmaxf(d[6], 0.f), h_hi[2],
                       fmaxf(d[7], 0.f) * h_hi[3])))))));
        s += __shfl_xor(s, 32);                  // sum the two k-halves
        float w = __builtin_amdgcn_exp2f(s);
        if (k == lastk) w = (n < PP - (NT - 1) * 32) ? w : 0.f;
        z += w;
        p0 = fmaf(w, m0, p0); p1 = fmaf(w, m1, p1);
        p2 = fmaf(w, m2, p2); p3 = fmaf(w, m3, p3);
        p4 = fmaf(w, m4, p4); p5 = fmaf(w, m5, p5);
        p6 = fmaf(w, m6, p6); p7 = fmaf(w, m7, p7);
    }

    // ---- per-wave reduce, then cross-wave combine ----
    const float4 pf0 = ((const float4*)pp_)[2 * h];
    const float4 pf1 = ((const float4*)pp_)[2 * h + 1];
    float awp = fmaf(p0, pf0.x, fmaf(p1, pf0.y, fmaf(p2, pf0.z,
                fmaf(p3, pf0.w, fmaf(p4, pf1.x, fmaf(p5, pf1.y,
                fmaf(p6, pf1.z, p7 * pf1.w)))))));
    #pragma unroll
    for (int m = 1; m < 64; m <<= 1) {
        awp += __shfl_xor(awp, m);
        z   += __shfl_xor(z, m);
    }
    if (lane == 0) { s_red[wid][0] = awp; s_red[wid][1] = z; }
    __syncthreads();
    if (wh == 0 && lane == 0) {
        // wave-pair sums: aw = awp0+awp1 (each e-half once), 2Z = z0+z1
        float aw = s_red[wid][0] + s_red[wid + 1][0];
        float zz = s_red[wid][1] + s_red[wid + 1][1];
        float y = bias[0] + fo + 2.f * aw / zz;
        out[smp] = 1.f / (1.f + __expf(-y));
    }
}

extern "C" void kernel_launch(void* const* d_in, const int* in_sizes, int n_in,
                              void* d_out, int out_size, void* d_ws, size_t ws_size,
                              hipStream_t stream) {
    const int*   fidx      = (const int*)  d_in[0];
    const float* fval      = (const float*)d_in[1];
    const float* fow       = (const float*)d_in[2];
    const float* emb_table = (const float*)d_in[3];
    const float* bias      = (const float*)d_in[4];
    const float* attn_w    = (const float*)d_in[5];
    const float* attn_b    = (const float*)d_in[6];
    const float* proj_h    = (const float*)d_in[7];
    const float* proj_p    = (const float*)d_in[8];
    float* out = (float*)d_out;

    afm_kernel<<<BB / 2, 256, 0, stream>>>(fidx, fval, fow, emb_table, bias,
                                           attn_w, attn_b, proj_h, proj_p, out);
}

// Round 7
// 134.709 us; speedup vs baseline: 2.2616x; 2.2616x over previous
//
#include <hip/hip_runtime.h>
#include <math.h>

// AFM forward, round 7: r6's two-waves-per-sample structure with the register
// cap FIXED. r6's launch_bounds(256,8) forced VGPR<=64 -> full spill to
// scratch (FETCH 469 MB, WRITE 326 MB, 211 us). Same kernel at (256,4)
// (VGPR<=128, no spill) is the clean A/B of the latency-split idea vs r5.
// Per-tile math bit-identical to r5: bf16 rows in LDS, 32x32x16 MFMA (K=16
// exact), v_perm packs, exp2 with pre-scaled proj_h, fp32 pooling.

#define BB 8192
#define FF 39
#define PP 741
#define NT 24                 // total 32-pair tiles per sample
#define NTW 12                // tiles per wave (2 waves per sample)
#define RBYTES 48             // bf16 row stride: 32B data + 16B pad
#define SBYTES (FF * RBYTES)  // 1872 B per sample

typedef short bf16x8 __attribute__((ext_vector_type(8)));
typedef float f32x4  __attribute__((ext_vector_type(4)));
typedef float f32x16 __attribute__((ext_vector_type(16)));

// pack two fp32 -> dword of two bf16 (truncation), single v_perm_b32
static __device__ __forceinline__ unsigned pack2(float lo, float hi) {
    return __builtin_amdgcn_perm(__builtin_bit_cast(unsigned, hi),
                                 __builtin_bit_cast(unsigned, lo),
                                 0x07060302u);
}
static __device__ __forceinline__ float up_lo(unsigned d) {
    return __builtin_bit_cast(float, d << 16);
}
static __device__ __forceinline__ float up_hi(unsigned d) {
    return __builtin_bit_cast(float, d & 0xFFFF0000u);
}

__global__ __launch_bounds__(256, 4)
void afm_kernel(const int*   __restrict__ fidx,
                const float* __restrict__ fval,
                const float* __restrict__ fow,
                const float* __restrict__ emb,
                const float* __restrict__ bias,
                const float* __restrict__ aw_,   // [E=16][A=16] row-major
                const float* __restrict__ ab_,   // [16]
                const float* __restrict__ ph_,   // [16]
                const float* __restrict__ pp_,   // [16]
                float*       __restrict__ out)
{
    __shared__ __align__(16) unsigned char s_emb[2 * SBYTES];  // 3744 B
    __shared__ unsigned s_pij[NT * 32];                        // 3072 B
    __shared__ float s_red[4][2];                              // per-wave aw,z

    const int tid  = threadIdx.x;
    const int wid  = tid >> 6;
    const int lane = tid & 63;
    const int n    = lane & 31;      // pair slot within tile
    const int h    = lane >> 5;      // e-half / k-half
    const int ws   = wid >> 1;       // sample slot in block (0/1)
    const int wh   = wid & 1;        // wave-half within sample
    const int smp  = blockIdx.x * 2 + ws;

    // ---- pair table (block-shared): (i*48)<<16 | (j*48) byte offsets ----
    if (tid < FF - 1) {
        int i = tid;
        int base = (i * (2 * FF - i - 1)) >> 1;
        for (int j = i + 1; j < FF; ++j)
            s_pij[base++] = ((unsigned)(i * RBYTES) << 16) | (unsigned)(j * RBYTES);
    } else if (tid == FF - 1) {
        for (int e = PP; e < NT * 32; ++e) s_pij[e] = 0u;  // dead slots
    }

    // ---- per-sample: indices/values (both waves), first-order (even wave) --
    int ixr = 0; float vr = 0.f, fo = 0.f;
    if (lane < FF) {
        ixr = fidx[smp * FF + lane];
        vr  = fval[smp * FF + lane];
    }
    if (wh == 0) {
        if (lane < FF) fo = fow[ixr] * vr;
        #pragma unroll
        for (int m = 1; m < 64; m <<= 1) fo += __shfl_xor(fo, m);
    }

    // ---- stage scaled rows as bf16: 78 half-row tasks over the 2 waves ----
    unsigned char* my = s_emb + ws * SBYTES;
    {
        int u = lane + 64 * wh;
        if (u < FF * 2) {
            int row = u >> 1, hh = u & 1;
            int   ix = __shfl(ixr, row);
            float v  = __shfl(vr,  row);
            const float4* src = (const float4*)emb + (size_t)ix * 4 + hh * 2;
            float4 e0 = src[0], e1 = src[1];
            uint4 d = make_uint4(pack2(e0.x * v, e0.y * v),
                                 pack2(e0.z * v, e0.w * v),
                                 pack2(e1.x * v, e1.y * v),
                                 pack2(e1.z * v, e1.w * v));
            *(uint4*)(my + row * RBYTES + hh * 16) = d;
        }
    }

    // ---- constant fragments ----
    const float LOG2E = 1.44269504088896f;
    f32x4 h_lo = ((const f32x4*)ph_)[h];        // a = 4h + reg      (regs 0-3)
    f32x4 h_hi = ((const f32x4*)ph_)[h + 2];    // a = 8 + 4h + reg  (regs 4-7)
    #pragma unroll
    for (int r = 0; r < 4; ++r) { h_lo[r] *= LOG2E; h_hi[r] *= LOG2E; }

    f32x16 cinit;                               // bias rows a<16, zero above
    {
        const f32x4 ab_lo = ((const f32x4*)ab_)[h];
        const f32x4 ab_hi = ((const f32x4*)ab_)[h + 2];
        cinit[0] = ab_lo[0]; cinit[1] = ab_lo[1];
        cinit[2] = ab_lo[2]; cinit[3] = ab_lo[3];
        cinit[4] = ab_hi[0]; cinit[5] = ab_hi[1];
        cinit[6] = ab_hi[2]; cinit[7] = ab_hi[3];
        #pragma unroll
        for (int r = 8; r < 16; ++r) cinit[r] = 0.f;
    }

    bf16x8 wfrag;                               // A = W^T, rows m>=16 zero
    {
        float t0 = 0.f, t1 = 0.f, t2 = 0.f, t3 = 0.f,
              t4 = 0.f, t5 = 0.f, t6 = 0.f, t7 = 0.f;
        if (n < 16) {
            const float* base = aw_ + (8 * h) * 16 + n;  // W[k=8h+j][m=n]
            t0 = base[0];   t1 = base[16];  t2 = base[32];  t3 = base[48];
            t4 = base[64];  t5 = base[80];  t6 = base[96];  t7 = base[112];
        }
        union { unsigned i[4]; bf16x8 v; } u;
        u.i[0] = pack2(t0, t1); u.i[1] = pack2(t2, t3);
        u.i[2] = pack2(t4, t5); u.i[3] = pack2(t6, t7);
        wfrag = u.v;
    }

    __syncthreads();   // staging (cross-wave within sample) + s_pij

    // ---- main loop: this wave's 12 tiles (t = wh + 2k) ----
    const unsigned char* bpre = my + h * 16;    // this lane's e-half
    const unsigned* pijp = s_pij + wh * 32 + n; // stride 64 dwords per k
    float p0=0.f,p1=0.f,p2=0.f,p3=0.f,p4=0.f,p5=0.f,p6=0.f,p7=0.f;
    float z = 0.f;
    // last global tile (t=23) is held by wh==1, k==11; valid pairs: n < 5
    const int lastk = (wh == 1) ? (NTW - 1) : NTW;

    #pragma unroll 4
    for (int k = 0; k < NTW; ++k) {
        unsigned pk = pijp[k * 64];
        uint4 di = *(const uint4*)(bpre + (pk >> 16));
        uint4 dj = *(const uint4*)(bpre + (pk & 0xFFFFu));
        float m0 = up_lo(di.x) * up_lo(dj.x);
        float m1 = up_hi(di.x) * up_hi(dj.x);
        float m2 = up_lo(di.y) * up_lo(dj.y);
        float m3 = up_hi(di.y) * up_hi(dj.y);
        float m4 = up_lo(di.z) * up_lo(dj.z);
        float m5 = up_hi(di.z) * up_hi(dj.z);
        float m6 = up_lo(di.w) * up_lo(dj.w);
        float m7 = up_hi(di.w) * up_hi(dj.w);
        union { unsigned i[4]; bf16x8 v; } u;
        u.i[0] = pack2(m0, m1); u.i[1] = pack2(m2, m3);
        u.i[2] = pack2(m4, m5); u.i[3] = pack2(m6, m7);
        f32x16 d = __builtin_amdgcn_mfma_f32_32x32x16_bf16(wfrag, u.v,
                                                           cinit, 0, 0, 0);
        float s = fmaf(fmaxf(d[0], 0.f), h_lo[0],
                  fmaf(fmaxf(d[1], 0.f), h_lo[1],
                  fmaf(fmaxf(d[2], 0.f), h_lo[2],
                  fmaf(fmaxf(d[3], 0.f), h_lo[3],
                  fmaf(fmaxf(d[4], 0.f), h_hi[0],
                  fmaf(fmaxf(d[5], 0.f), h_hi[1],
                  fmaf(fmaxf(d[6], 0.f), h_hi[2],
                       fmaxf(d[7], 0.f) * h_hi[3])))))));
        s += __shfl_xor(s, 32);                  // sum the two k-halves
        float w = __builtin_amdgcn_exp2f(s);
        if (k == lastk) w = (n < PP - (NT - 1) * 32) ? w : 0.f;
        z += w;
        p0 = fmaf(w, m0, p0); p1 = fmaf(w, m1, p1);
        p2 = fmaf(w, m2, p2); p3 = fmaf(w, m3, p3);
        p4 = fmaf(w, m4, p4); p5 = fmaf(w, m5, p5);
        p6 = fmaf(w, m6, p6); p7 = fmaf(w, m7, p7);
    }

    // ---- per-wave reduce, then cross-wave combine ----
    const float4 pf0 = ((const float4*)pp_)[2 * h];
    const float4 pf1 = ((const float4*)pp_)[2 * h + 1];
    float awp = fmaf(p0, pf0.x, fmaf(p1, pf0.y, fmaf(p2, pf0.z,
                fmaf(p3, pf0.w, fmaf(p4, pf1.x, fmaf(p5, pf1.y,
                fmaf(p6, pf1.z, p7 * pf1.w)))))));
    #pragma unroll
    for (int m = 1; m < 64; m <<= 1) {
        awp += __shfl_xor(awp, m);
        z   += __shfl_xor(z, m);
    }
    if (lane == 0) { s_red[wid][0] = awp; s_red[wid][1] = z; }
    __syncthreads();
    if (wh == 0 && lane == 0) {
        // wave-pair sums: aw = awp0+awp1 (each e-half once), 2Z = z0+z1
        float aw = s_red[wid][0] + s_red[wid + 1][0];
        float zz = s_red[wid][1] + s_red[wid + 1][1];
        float y = bias[0] + fo + 2.f * aw / zz;
        out[smp] = 1.f / (1.f + __expf(-y));
    }
}

extern "C" void kernel_launch(void* const* d_in, const int* in_sizes, int n_in,
                              void* d_out, int out_size, void* d_ws, size_t ws_size,
                              hipStream_t stream) {
    const int*   fidx      = (const int*)  d_in[0];
    const float* fval      = (const float*)d_in[1];
    const float* fow       = (const float*)d_in[2];
    const float* emb_table = (const float*)d_in[3];
    const float* bias      = (const float*)d_in[4];
    const float* attn_w    = (const float*)d_in[5];
    const float* attn_b    = (const float*)d_in[6];
    const float* proj_h    = (const float*)d_in[7];
    const float* proj_p    = (const float*)d_in[8];
    float* out = (float*)d_out;

    afm_kernel<<<BB / 2, 256, 0, stream>>>(fidx, fval, fow, emb_table, bias,
                                           attn_w, attn_b, proj_h, proj_p, out);
}

// Round 8
// 132.320 us; speedup vs baseline: 2.3024x; 1.0180x over previous
//
#include <hip/hip_runtime.h>
#include <math.h>

// AFM forward, round 8: ZERO barriers. r5/r7 showed the kernel ignores LDS
// traffic, VALU mix, and chain-length changes -> the shared factor was the
// __syncthreads phase coupling (barrier drains every wave's random gather
// before any wave computes). This version: one wave per sample (s_emb is
// same-wave write->read, no barrier needed), and the pair table is a
// compile-time __device__ constexpr array (it's static!) preloaded into
// registers via 6 dwordx4 loads -> s_pij LDS + its barrier gone entirely.
// Per-tile math bit-identical to r5: bf16 rows in LDS, 32x32x16 MFMA (K=16
// exact), v_perm packs, exp2 with pre-scaled proj_h, fp32 pooling.

#define BB 8192
#define FF 39
#define PP 741
#define NT 24                 // 32-pair tiles per sample; tile 23 has 5 valid
#define RBYTES 48             // bf16 row stride: 32B data + 16B pad
#define SBYTES (FF * RBYTES)  // 1872 B per sample

typedef short bf16x8 __attribute__((ext_vector_type(8)));
typedef float f32x4  __attribute__((ext_vector_type(4)));
typedef float f32x16 __attribute__((ext_vector_type(16)));

// static pair table, transposed: v[n][k] = byte offsets of pair p = k*32+n,
// packed (i*RBYTES)<<16 | (j*RBYTES). Dead slots (p>=741) stay 0 (masked).
struct alignas(16) PijT { unsigned v[32][NT]; };
static constexpr PijT make_pij() {
    PijT t{};
    int p = 0;
    for (int i = 0; i < FF; ++i)
        for (int j = i + 1; j < FF; ++j) {
            t.v[p & 31][p >> 5] =
                ((unsigned)(i * RBYTES) << 16) | (unsigned)(j * RBYTES);
            ++p;
        }
    return t;
}
__device__ constexpr PijT c_pij = make_pij();

// pack two fp32 -> dword of two bf16 (truncation), single v_perm_b32
static __device__ __forceinline__ unsigned pack2(float lo, float hi) {
    return __builtin_amdgcn_perm(__builtin_bit_cast(unsigned, hi),
                                 __builtin_bit_cast(unsigned, lo),
                                 0x07060302u);
}
static __device__ __forceinline__ float up_lo(unsigned d) {
    return __builtin_bit_cast(float, d << 16);
}
static __device__ __forceinline__ float up_hi(unsigned d) {
    return __builtin_bit_cast(float, d & 0xFFFF0000u);
}

__global__ __launch_bounds__(256, 4)
void afm_kernel(const int*   __restrict__ fidx,
                const float* __restrict__ fval,
                const float* __restrict__ fow,
                const float* __restrict__ emb,
                const float* __restrict__ bias,
                const float* __restrict__ aw_,   // [E=16][A=16] row-major
                const float* __restrict__ ab_,   // [16]
                const float* __restrict__ ph_,   // [16]
                const float* __restrict__ pp_,   // [16]
                float*       __restrict__ out)
{
    __shared__ __align__(16) unsigned char s_emb[4 * SBYTES];  // 7488 B

    const int tid  = threadIdx.x;
    const int wid  = tid >> 6;
    const int lane = tid & 63;
    const int n    = lane & 31;      // pair slot within tile
    const int h    = lane >> 5;      // e-half / k-half
    const int smp  = blockIdx.x * 4 + wid;

    // ---- per-wave: indices + values ----
    int ixr = 0; float vr = 0.f;
    if (lane < FF) {
        ixr = fidx[smp * FF + lane];
        vr  = fval[smp * FF + lane];
    }

    // ---- stage scaled rows as bf16 (78 half-row tasks, same wave) ----
    unsigned char* my = s_emb + wid * SBYTES;
    for (int u = lane; u < FF * 2; u += 64) {
        int row = u >> 1, hh = u & 1;
        int   ix = __shfl(ixr, row);
        float v  = __shfl(vr,  row);
        const float4* src = (const float4*)emb + (size_t)ix * 4 + hh * 2;
        float4 e0 = src[0], e1 = src[1];
        uint4 d = make_uint4(pack2(e0.x * v, e0.y * v),
                             pack2(e0.z * v, e0.w * v),
                             pack2(e1.x * v, e1.y * v),
                             pack2(e1.z * v, e1.w * v));
        *(uint4*)(my + row * RBYTES + hh * 16) = d;
    }

    // ---- first-order term (overlaps the staging loads above) ----
    float fo = (lane < FF) ? fow[ixr] * vr : 0.f;
    #pragma unroll
    for (int m = 1; m < 64; m <<= 1) fo += __shfl_xor(fo, m);

    // ---- constant fragments ----
    const float LOG2E = 1.44269504088896f;
    f32x4 h_lo = ((const f32x4*)ph_)[h];        // a = 4h + reg      (regs 0-3)
    f32x4 h_hi = ((const f32x4*)ph_)[h + 2];    // a = 8 + 4h + reg  (regs 4-7)
    #pragma unroll
    for (int r = 0; r < 4; ++r) { h_lo[r] *= LOG2E; h_hi[r] *= LOG2E; }

    f32x16 cinit;                               // bias rows a<16, zero above
    {
        const f32x4 ab_lo = ((const f32x4*)ab_)[h];
        const f32x4 ab_hi = ((const f32x4*)ab_)[h + 2];
        cinit[0] = ab_lo[0]; cinit[1] = ab_lo[1];
        cinit[2] = ab_lo[2]; cinit[3] = ab_lo[3];
        cinit[4] = ab_hi[0]; cinit[5] = ab_hi[1];
        cinit[6] = ab_hi[2]; cinit[7] = ab_hi[3];
        #pragma unroll
        for (int r = 8; r < 16; ++r) cinit[r] = 0.f;
    }

    bf16x8 wfrag;                               // A = W^T, rows m>=16 zero
    {
        float t0 = 0.f, t1 = 0.f, t2 = 0.f, t3 = 0.f,
              t4 = 0.f, t5 = 0.f, t6 = 0.f, t7 = 0.f;
        if (n < 16) {
            const float* base = aw_ + (8 * h) * 16 + n;  // W[k=8h+j][m=n]
            t0 = base[0];   t1 = base[16];  t2 = base[32];  t3 = base[48];
            t4 = base[64];  t5 = base[80];  t6 = base[96];  t7 = base[112];
        }
        union { unsigned i[4]; bf16x8 v; } u;
        u.i[0] = pack2(t0, t1); u.i[1] = pack2(t2, t3);
        u.i[2] = pack2(t4, t5); u.i[3] = pack2(t6, t7);
        wfrag = u.v;
    }

    // ---- main loop: 24 tiles, pair offsets from the constexpr table ----
    const unsigned char* bpre = my + h * 16;    // this lane's e-half
    const uint4* myp4 = (const uint4*)c_pij.v[n];   // 6 x 16B, L1-resident
    float p0=0.f,p1=0.f,p2=0.f,p3=0.f,p4=0.f,p5=0.f,p6=0.f,p7=0.f;
    float z = 0.f;

#define TILE(PK, MASKED)                                                  \
    {                                                                     \
        unsigned pk = (PK);                                               \
        uint4 di = *(const uint4*)(bpre + (pk >> 16));                    \
        uint4 dj = *(const uint4*)(bpre + (pk & 0xFFFFu));                \
        float m0 = up_lo(di.x) * up_lo(dj.x);                             \
        float m1 = up_hi(di.x) * up_hi(dj.x);                             \
        float m2 = up_lo(di.y) * up_lo(dj.y);                             \
        float m3 = up_hi(di.y) * up_hi(dj.y);                             \
        float m4 = up_lo(di.z) * up_lo(dj.z);                             \
        float m5 = up_hi(di.z) * up_hi(dj.z);                             \
        float m6 = up_lo(di.w) * up_lo(dj.w);                             \
        float m7 = up_hi(di.w) * up_hi(dj.w);                             \
        union { unsigned i[4]; bf16x8 v; } u;                             \
        u.i[0] = pack2(m0, m1); u.i[1] = pack2(m2, m3);                   \
        u.i[2] = pack2(m4, m5); u.i[3] = pack2(m6, m7);                   \
        f32x16 d = __builtin_amdgcn_mfma_f32_32x32x16_bf16(wfrag, u.v,    \
                                                           cinit, 0, 0, 0); \
        float s = fmaf(fmaxf(d[0], 0.f), h_lo[0],                         \
                  fmaf(fmaxf(d[1], 0.f), h_lo[1],                         \
                  fmaf(fmaxf(d[2], 0.f), h_lo[2],                         \
                  fmaf(fmaxf(d[3], 0.f), h_lo[3],                         \
                  fmaf(fmaxf(d[4], 0.f), h_hi[0],                         \
                  fmaf(fmaxf(d[5], 0.f), h_hi[1],                         \
                  fmaf(fmaxf(d[6], 0.f), h_hi[2],                         \
                       fmaxf(d[7], 0.f) * h_hi[3])))))));                 \
        s += __shfl_xor(s, 32);                                           \
        float w = __builtin_amdgcn_exp2f(s);                              \
        if (MASKED) w = (n < PP - (NT - 1) * 32) ? w : 0.f;               \
        z += w;                                                           \
        p0 = fmaf(w, m0, p0); p1 = fmaf(w, m1, p1);                       \
        p2 = fmaf(w, m2, p2); p3 = fmaf(w, m3, p3);                       \
        p4 = fmaf(w, m4, p4); p5 = fmaf(w, m5, p5);                       \
        p6 = fmaf(w, m6, p6); p7 = fmaf(w, m7, p7);                       \
    }

    #pragma unroll
    for (int g = 0; g < 6; ++g) {
        uint4 q = myp4[g];
        TILE(q.x, false);
        TILE(q.y, false);
        TILE(q.z, false);
        TILE(q.w, g == 5);
    }
#undef TILE

    // ---- epilogue: aw = pooled . p, full-wave reduce, lane 0 stores ----
    const float4 pf0 = ((const float4*)pp_)[2 * h];
    const float4 pf1 = ((const float4*)pp_)[2 * h + 1];
    float awp = fmaf(p0, pf0.x, fmaf(p1, pf0.y, fmaf(p2, pf0.z,
                fmaf(p3, pf0.w, fmaf(p4, pf1.x, fmaf(p5, pf1.y,
                fmaf(p6, pf1.z, p7 * pf1.w)))))));
    #pragma unroll
    for (int m = 1; m < 64; m <<= 1) {
        awp += __shfl_xor(awp, m);
        z   += __shfl_xor(z, m);
    }
    if (lane == 0) {
        // lane-sum awp = aw (each e-half once); lane-sum z = 2*Z.
        float y = bias[0] + fo + 2.f * awp / z;
        out[smp] = 1.f / (1.f + __expf(-y));
    }
}

extern "C" void kernel_launch(void* const* d_in, const int* in_sizes, int n_in,
                              void* d_out, int out_size, void* d_ws, size_t ws_size,
                              hipStream_t stream) {
    const int*   fidx      = (const int*)  d_in[0];
    const float* fval      = (const float*)d_in[1];
    const float* fow       = (const float*)d_in[2];
    const float* emb_table = (const float*)d_in[3];
    const float* bias      = (const float*)d_in[4];
    const float* attn_w    = (const float*)d_in[5];
    const float* attn_b    = (const float*)d_in[6];
    const float* proj_h    = (const float*)d_in[7];
    const float* proj_p    = (const float*)d_in[8];
    float* out = (float*)d_out;

    afm_kernel<<<BB / 4, 256, 0, stream>>>(fidx, fval, fow, emb_table, bias,
                                           attn_w, attn_b, proj_h, proj_p, out);
}

// Round 10
// 128.725 us; speedup vs baseline: 2.3667x; 1.0279x over previous
//
#include <hip/hip_runtime.h>
#include <hip/hip_fp16.h>
#include <math.h>

// AFM forward, round 10 = round 9 with the cvt_pkrtz return-type fixed
// (bit_cast from __fp16x2 to _Float16x2). Packed-fp16 VALU: rows stored as
// fp16 in LDS; pair products = 4x v_pk_mul_f16 (result IS the MFMA B-frag);
// pooling = 4x v_pk_fma_f16; mfma_f32_32x32x16_f16. Zero barriers, constexpr
// pair table, one wave per sample (r8 structure).

#define BB 8192
#define FF 39
#define PP 741
#define NT 24                 // 32-pair tiles per sample; tile 23 has 5 valid
#define RBYTES 48             // fp16 row stride: 32B data + 16B pad
#define SBYTES (FF * RBYTES)  // 1872 B per sample

typedef _Float16 f16x8 __attribute__((ext_vector_type(8)));
typedef _Float16 h2    __attribute__((ext_vector_type(2)));
typedef float    f32x4  __attribute__((ext_vector_type(4)));
typedef float    f32x16 __attribute__((ext_vector_type(16)));

// static pair table, transposed: v[n][k] = byte offsets of pair p = k*32+n,
// packed (i*RBYTES)<<16 | (j*RBYTES). Dead slots (p>=741) stay 0 (masked).
struct alignas(16) PijT { unsigned v[32][NT]; };
static constexpr PijT make_pij() {
    PijT t{};
    int p = 0;
    for (int i = 0; i < FF; ++i)
        for (int j = i + 1; j < FF; ++j) {
            t.v[p & 31][p >> 5] =
                ((unsigned)(i * RBYTES) << 16) | (unsigned)(j * RBYTES);
            ++p;
        }
    return t;
}
__device__ constexpr PijT c_pij = make_pij();

static __device__ __forceinline__ h2 cvt2(float lo, float hi) {
    return __builtin_bit_cast(h2, __builtin_amdgcn_cvt_pkrtz(lo, hi));
}
static __device__ __forceinline__ h2 ash2(unsigned d) {
    return __builtin_bit_cast(h2, d);
}

__global__ __launch_bounds__(256, 4)
void afm_kernel(const int*   __restrict__ fidx,
                const float* __restrict__ fval,
                const float* __restrict__ fow,
                const float* __restrict__ emb,
                const float* __restrict__ bias,
                const float* __restrict__ aw_,   // [E=16][A=16] row-major
                const float* __restrict__ ab_,   // [16]
                const float* __restrict__ ph_,   // [16]
                const float* __restrict__ pp_,   // [16]
                float*       __restrict__ out)
{
    __shared__ __align__(16) unsigned char s_emb[4 * SBYTES];  // 7488 B

    const int tid  = threadIdx.x;
    const int wid  = tid >> 6;
    const int lane = tid & 63;
    const int n    = lane & 31;      // pair slot within tile
    const int h    = lane >> 5;      // e-half / k-half
    const int smp  = blockIdx.x * 4 + wid;

    // ---- per-wave: indices + values ----
    int ixr = 0; float vr = 0.f;
    if (lane < FF) {
        ixr = fidx[smp * FF + lane];
        vr  = fval[smp * FF + lane];
    }

    // ---- stage scaled rows as fp16 (78 half-row tasks, same wave) ----
    unsigned char* my = s_emb + wid * SBYTES;
    for (int u = lane; u < FF * 2; u += 64) {
        int row = u >> 1, hh = u & 1;
        int   ix = __shfl(ixr, row);
        float v  = __shfl(vr,  row);
        const float4* src = (const float4*)emb + (size_t)ix * 4 + hh * 2;
        float4 e0 = src[0], e1 = src[1];
        h2 a0 = cvt2(e0.x * v, e0.y * v);
        h2 a1 = cvt2(e0.z * v, e0.w * v);
        h2 a2 = cvt2(e1.x * v, e1.y * v);
        h2 a3 = cvt2(e1.z * v, e1.w * v);
        uint4 d = make_uint4(__builtin_bit_cast(unsigned, a0),
                             __builtin_bit_cast(unsigned, a1),
                             __builtin_bit_cast(unsigned, a2),
                             __builtin_bit_cast(unsigned, a3));
        *(uint4*)(my + row * RBYTES + hh * 16) = d;
    }

    // ---- first-order term (overlaps the staging loads above) ----
    float fo = (lane < FF) ? fow[ixr] * vr : 0.f;
    #pragma unroll
    for (int m = 1; m < 64; m <<= 1) fo += __shfl_xor(fo, m);

    // ---- constant fragments ----
    const float LOG2E = 1.44269504088896f;
    f32x4 h_lo = ((const f32x4*)ph_)[h];        // a = 4h + reg      (regs 0-3)
    f32x4 h_hi = ((const f32x4*)ph_)[h + 2];    // a = 8 + 4h + reg  (regs 4-7)
    #pragma unroll
    for (int r = 0; r < 4; ++r) { h_lo[r] *= LOG2E; h_hi[r] *= LOG2E; }

    f32x16 cinit;                               // bias rows a<16, zero above
    {
        const f32x4 ab_lo = ((const f32x4*)ab_)[h];
        const f32x4 ab_hi = ((const f32x4*)ab_)[h + 2];
        cinit[0] = ab_lo[0]; cinit[1] = ab_lo[1];
        cinit[2] = ab_lo[2]; cinit[3] = ab_lo[3];
        cinit[4] = ab_hi[0]; cinit[5] = ab_hi[1];
        cinit[6] = ab_hi[2]; cinit[7] = ab_hi[3];
        #pragma unroll
        for (int r = 8; r < 16; ++r) cinit[r] = 0.f;
    }

    f16x8 wfrag;                                // A = W^T, rows m>=16 zero
    {
        float t0 = 0.f, t1 = 0.f, t2 = 0.f, t3 = 0.f,
              t4 = 0.f, t5 = 0.f, t6 = 0.f, t7 = 0.f;
        if (n < 16) {
            const float* base = aw_ + (8 * h) * 16 + n;  // W[k=8h+j][m=n]
            t0 = base[0];   t1 = base[16];  t2 = base[32];  t3 = base[48];
            t4 = base[64];  t5 = base[80];  t6 = base[96];  t7 = base[112];
        }
        union { h2 hh[4]; f16x8 v; } u;
        u.hh[0] = cvt2(t0, t1); u.hh[1] = cvt2(t2, t3);
        u.hh[2] = cvt2(t4, t5); u.hh[3] = cvt2(t6, t7);
        wfrag = u.v;
    }

    // ---- main loop: 24 tiles, pair offsets from the constexpr table ----
    const unsigned char* bpre = my + h * 16;    // this lane's e-half
    const uint4* myp4 = (const uint4*)c_pij.v[n];   // 6 x 16B, L1-resident
    h2 q0 = {0.f, 0.f}, q1 = {0.f, 0.f}, q2 = {0.f, 0.f}, q3 = {0.f, 0.f};
    float z = 0.f;

#define TILE(PK, MASKED)                                                  \
    {                                                                     \
        unsigned pk = (PK);                                               \
        uint4 di = *(const uint4*)(bpre + (pk >> 16));                    \
        uint4 dj = *(const uint4*)(bpre + (pk & 0xFFFFu));                \
        h2 m0 = ash2(di.x) * ash2(dj.x);     /* v_pk_mul_f16 */           \
        h2 m1 = ash2(di.y) * ash2(dj.y);                                  \
        h2 m2 = ash2(di.z) * ash2(dj.z);                                  \
        h2 m3 = ash2(di.w) * ash2(dj.w);                                  \
        union { h2 hh[4]; f16x8 v; } u;                                   \
        u.hh[0] = m0; u.hh[1] = m1; u.hh[2] = m2; u.hh[3] = m3;           \
        f32x16 d = __builtin_amdgcn_mfma_f32_32x32x16_f16(wfrag, u.v,     \
                                                          cinit, 0, 0, 0); \
        float s = fmaf(fmaxf(d[0], 0.f), h_lo[0],                         \
                  fmaf(fmaxf(d[1], 0.f), h_lo[1],                         \
                  fmaf(fmaxf(d[2], 0.f), h_lo[2],                         \
                  fmaf(fmaxf(d[3], 0.f), h_lo[3],                         \
                  fmaf(fmaxf(d[4], 0.f), h_hi[0],                         \
                  fmaf(fmaxf(d[5], 0.f), h_hi[1],                         \
                  fmaf(fmaxf(d[6], 0.f), h_hi[2],                         \
                       fmaxf(d[7], 0.f) * h_hi[3])))))));                 \
        s += __shfl_xor(s, 32);                                           \
        float w = __builtin_amdgcn_exp2f(s);                              \
        if (MASKED) w = (n < PP - (NT - 1) * 32) ? w : 0.f;               \
        z += w;                                                           \
        h2 w2 = cvt2(w, w);                  /* one cvt_pkrtz */          \
        q0 += w2 * m0; q1 += w2 * m1;        /* v_pk_fma_f16 */           \
        q2 += w2 * m2; q3 += w2 * m3;                                     \
    }

    #pragma unroll
    for (int g = 0; g < 6; ++g) {
        uint4 q = myp4[g];
        TILE(q.x, false);
        TILE(q.y, false);
        TILE(q.z, false);
        TILE(q.w, g == 5);
    }
#undef TILE

    // ---- epilogue: unpack pooled fp16 -> fp32, dot with proj_p, reduce ----
    const float4 pf0 = ((const float4*)pp_)[2 * h];
    const float4 pf1 = ((const float4*)pp_)[2 * h + 1];
    float awp = fmaf((float)q0[0], pf0.x, fmaf((float)q0[1], pf0.y,
                fmaf((float)q1[0], pf0.z, fmaf((float)q1[1], pf0.w,
                fmaf((float)q2[0], pf1.x, fmaf((float)q2[1], pf1.y,
                fmaf((float)q3[0], pf1.z, (float)q3[1] * pf1.w)))))));
    #pragma unroll
    for (int m = 1; m < 64; m <<= 1) {
        awp += __shfl_xor(awp, m);
        z   += __shfl_xor(z, m);
    }
    if (lane == 0) {
        // lane-sum awp = aw (each e-half once); lane-sum z = 2*Z.
        float y = bias[0] + fo + 2.f * awp / z;
        out[smp] = 1.f / (1.f + __expf(-y));
    }
}

extern "C" void kernel_launch(void* const* d_in, const int* in_sizes, int n_in,
                              void* d_out, int out_size, void* d_ws, size_t ws_size,
                              hipStream_t stream) {
    const int*   fidx      = (const int*)  d_in[0];
    const float* fval      = (const float*)d_in[1];
    const float* fow       = (const float*)d_in[2];
    const float* emb_table = (const float*)d_in[3];
    const float* bias      = (const float*)d_in[4];
    const float* attn_w    = (const float*)d_in[5];
    const float* attn_b    = (const float*)d_in[6];
    const float* proj_h    = (const float*)d_in[7];
    const float* proj_p    = (const float*)d_in[8];
    float* out = (float*)d_out;

    afm_kernel<<<BB / 4, 256, 0, stream>>>(fidx, fval, fow, emb_table, bias,
                                           attn_w, attn_b, proj_h, proj_p, out);
}

// Round 11
// 126.685 us; speedup vs baseline: 2.4048x; 1.0161x over previous
//
#include <hip/hip_runtime.h>
#include <hip/hip_fp16.h>
#include <math.h>

// AFM forward, round 11: r10 + (a) explicit 1-tile-ahead LDS prefetch (all 24
// pair offsets preloaded to registers; tile t+1's ds_read_b128 pair issues
// before tile t's MFMA/score chain) and (b) packed-fp16 score reduction
// (cvt_pkrtz + v_pk_max_f16 + chained v_dot2_f32_f16: 12 ops, 4-deep chain,
// vs 16 ops / 8-deep). Zero barriers, constexpr pair table, one wave per
// sample, fp16 rows in LDS, mfma_f32_32x32x16_f16, fp32 z / fp16 pooling.

#define BB 8192
#define FF 39
#define PP 741
#define NT 24                 // 32-pair tiles per sample; tile 23 has 5 valid
#define RBYTES 48             // fp16 row stride: 32B data + 16B pad
#define SBYTES (FF * RBYTES)  // 1872 B per sample

typedef _Float16 f16x8 __attribute__((ext_vector_type(8)));
typedef _Float16 h2    __attribute__((ext_vector_type(2)));
typedef __fp16   hw2   __attribute__((ext_vector_type(2)));  // builtin ABI type
typedef float    f32x4  __attribute__((ext_vector_type(4)));
typedef float    f32x16 __attribute__((ext_vector_type(16)));

// static pair table, transposed: v[n][k] = byte offsets of pair p = k*32+n,
// packed (i*RBYTES)<<16 | (j*RBYTES). Dead slots (p>=741) stay 0 (masked).
struct alignas(16) PijT { unsigned v[32][NT]; };
static constexpr PijT make_pij() {
    PijT t{};
    int p = 0;
    for (int i = 0; i < FF; ++i)
        for (int j = i + 1; j < FF; ++j) {
            t.v[p & 31][p >> 5] =
                ((unsigned)(i * RBYTES) << 16) | (unsigned)(j * RBYTES);
            ++p;
        }
    return t;
}
__device__ constexpr PijT c_pij = make_pij();

static __device__ __forceinline__ h2 cvt2(float lo, float hi) {
    return __builtin_bit_cast(h2, __builtin_amdgcn_cvt_pkrtz(lo, hi));
}
static __device__ __forceinline__ h2 ash2(unsigned d) {
    return __builtin_bit_cast(h2, d);
}
static __device__ __forceinline__ float fdot2f(h2 a, h2 b, float c) {
    return __builtin_amdgcn_fdot2(__builtin_bit_cast(hw2, a),
                                  __builtin_bit_cast(hw2, b), c, false);
}
static __device__ __forceinline__ h2 relu2(h2 x) {
    const h2 zz = {(_Float16)0.f, (_Float16)0.f};
    return __builtin_elementwise_max(x, zz);   // v_pk_max_f16
}

__global__ __launch_bounds__(256, 4)
void afm_kernel(const int*   __restrict__ fidx,
                const float* __restrict__ fval,
                const float* __restrict__ fow,
                const float* __restrict__ emb,
                const float* __restrict__ bias,
                const float* __restrict__ aw_,   // [E=16][A=16] row-major
                const float* __restrict__ ab_,   // [16]
                const float* __restrict__ ph_,   // [16]
                const float* __restrict__ pp_,   // [16]
                float*       __restrict__ out)
{
    __shared__ __align__(16) unsigned char s_emb[4 * SBYTES];  // 7488 B

    const int tid  = threadIdx.x;
    const int wid  = tid >> 6;
    const int lane = tid & 63;
    const int n    = lane & 31;      // pair slot within tile
    const int h    = lane >> 5;      // e-half / k-half
    const int smp  = blockIdx.x * 4 + wid;

    // ---- per-wave: indices + values ----
    int ixr = 0; float vr = 0.f;
    if (lane < FF) {
        ixr = fidx[smp * FF + lane];
        vr  = fval[smp * FF + lane];
    }

    // ---- stage scaled rows as fp16 (78 half-row tasks, same wave) ----
    unsigned char* my = s_emb + wid * SBYTES;
    for (int u = lane; u < FF * 2; u += 64) {
        int row = u >> 1, hh = u & 1;
        int   ix = __shfl(ixr, row);
        float v  = __shfl(vr,  row);
        const float4* src = (const float4*)emb + (size_t)ix * 4 + hh * 2;
        float4 e0 = src[0], e1 = src[1];
        h2 a0 = cvt2(e0.x * v, e0.y * v);
        h2 a1 = cvt2(e0.z * v, e0.w * v);
        h2 a2 = cvt2(e1.x * v, e1.y * v);
        h2 a3 = cvt2(e1.z * v, e1.w * v);
        uint4 d = make_uint4(__builtin_bit_cast(unsigned, a0),
                             __builtin_bit_cast(unsigned, a1),
                             __builtin_bit_cast(unsigned, a2),
                             __builtin_bit_cast(unsigned, a3));
        *(uint4*)(my + row * RBYTES + hh * 16) = d;
    }

    // ---- first-order term (overlaps the staging loads above) ----
    float fo = (lane < FF) ? fow[ixr] * vr : 0.f;
    #pragma unroll
    for (int m = 1; m < 64; m <<= 1) fo += __shfl_xor(fo, m);

    // ---- constant fragments ----
    const float LOG2E = 1.44269504088896f;
    // packed h coefficients (pre-scaled by log2 e), matching D-reg pair order:
    // regs 0..3 -> a = 4h + r ; regs 4..7 -> a = 8 + 4h + r
    h2 hp0, hp1, hp2, hp3;
    {
        const f32x4 lo = ((const f32x4*)ph_)[h];
        const f32x4 hi = ((const f32x4*)ph_)[h + 2];
        hp0 = cvt2(lo[0] * LOG2E, lo[1] * LOG2E);
        hp1 = cvt2(lo[2] * LOG2E, lo[3] * LOG2E);
        hp2 = cvt2(hi[0] * LOG2E, hi[1] * LOG2E);
        hp3 = cvt2(hi[2] * LOG2E, hi[3] * LOG2E);
    }

    f32x16 cinit;                               // bias rows a<16, zero above
    {
        const f32x4 ab_lo = ((const f32x4*)ab_)[h];
        const f32x4 ab_hi = ((const f32x4*)ab_)[h + 2];
        cinit[0] = ab_lo[0]; cinit[1] = ab_lo[1];
        cinit[2] = ab_lo[2]; cinit[3] = ab_lo[3];
        cinit[4] = ab_hi[0]; cinit[5] = ab_hi[1];
        cinit[6] = ab_hi[2]; cinit[7] = ab_hi[3];
        #pragma unroll
        for (int r = 8; r < 16; ++r) cinit[r] = 0.f;
    }

    f16x8 wfrag;                                // A = W^T, rows m>=16 zero
    {
        float t0 = 0.f, t1 = 0.f, t2 = 0.f, t3 = 0.f,
              t4 = 0.f, t5 = 0.f, t6 = 0.f, t7 = 0.f;
        if (n < 16) {
            const float* base = aw_ + (8 * h) * 16 + n;  // W[k=8h+j][m=n]
            t0 = base[0];   t1 = base[16];  t2 = base[32];  t3 = base[48];
            t4 = base[64];  t5 = base[80];  t6 = base[96];  t7 = base[112];
        }
        union { h2 hh[4]; f16x8 v; } u;
        u.hh[0] = cvt2(t0, t1); u.hh[1] = cvt2(t2, t3);
        u.hh[2] = cvt2(t4, t5); u.hh[3] = cvt2(t6, t7);
        wfrag = u.v;
    }

    // ---- preload all 24 pair offsets into registers (L1, 6 dwordx4) ----
    unsigned po[NT];
    {
        const uint4* myp4 = (const uint4*)c_pij.v[n];
        #pragma unroll
        for (int g = 0; g < 6; ++g) {
            uint4 q = myp4[g];
            po[4 * g + 0] = q.x; po[4 * g + 1] = q.y;
            po[4 * g + 2] = q.z; po[4 * g + 3] = q.w;
        }
    }

    // ---- main loop: 24 tiles, software-pipelined LDS reads (1 tile ahead) --
    const unsigned char* bpre = my + h * 16;    // this lane's e-half
    h2 q0 = {0.f, 0.f}, q1 = {0.f, 0.f}, q2 = {0.f, 0.f}, q3 = {0.f, 0.f};
    float z = 0.f;

    uint4 di = *(const uint4*)(bpre + (po[0] >> 16));
    uint4 dj = *(const uint4*)(bpre + (po[0] & 0xFFFFu));

    #pragma unroll
    for (int t = 0; t < NT; ++t) {
        uint4 diN = di, djN = dj;
        if (t + 1 < NT) {                        // compile-time under unroll
            diN = *(const uint4*)(bpre + (po[t + 1] >> 16));
            djN = *(const uint4*)(bpre + (po[t + 1] & 0xFFFFu));
        }
        h2 m0 = ash2(di.x) * ash2(dj.x);         // v_pk_mul_f16
        h2 m1 = ash2(di.y) * ash2(dj.y);
        h2 m2 = ash2(di.z) * ash2(dj.z);
        h2 m3 = ash2(di.w) * ash2(dj.w);
        union { h2 hh[4]; f16x8 v; } u;
        u.hh[0] = m0; u.hh[1] = m1; u.hh[2] = m2; u.hh[3] = m3;
        f32x16 d = __builtin_amdgcn_mfma_f32_32x32x16_f16(wfrag, u.v,
                                                          cinit, 0, 0, 0);
        h2 c0 = relu2(cvt2(d[0], d[1]));
        h2 c1 = relu2(cvt2(d[2], d[3]));
        h2 c2 = relu2(cvt2(d[4], d[5]));
        h2 c3 = relu2(cvt2(d[6], d[7]));
        float s = fdot2f(c0, hp0,
                  fdot2f(c1, hp1,
                  fdot2f(c2, hp2,
                  fdot2f(c3, hp3, 0.f))));       // v_dot2_f32_f16 x4
        s += __shfl_xor(s, 32);                  // sum the two k-halves
        float w = __builtin_amdgcn_exp2f(s);
        if (t == NT - 1) w = (n < PP - (NT - 1) * 32) ? w : 0.f;
        z += w;
        h2 w2 = cvt2(w, w);
        q0 += w2 * m0; q1 += w2 * m1;            // v_pk_fma_f16
        q2 += w2 * m2; q3 += w2 * m3;
        di = diN; dj = djN;
    }

    // ---- epilogue: unpack pooled fp16 -> fp32, dot with proj_p, reduce ----
    const float4 pf0 = ((const float4*)pp_)[2 * h];
    const float4 pf1 = ((const float4*)pp_)[2 * h + 1];
    float awp = fmaf((float)q0[0], pf0.x, fmaf((float)q0[1], pf0.y,
                fmaf((float)q1[0], pf0.z, fmaf((float)q1[1], pf0.w,
                fmaf((float)q2[0], pf1.x, fmaf((float)q2[1], pf1.y,
                fmaf((float)q3[0], pf1.z, (float)q3[1] * pf1.w)))))));
    #pragma unroll
    for (int m = 1; m < 64; m <<= 1) {
        awp += __shfl_xor(awp, m);
        z   += __shfl_xor(z, m);
    }
    if (lane == 0) {
        // lane-sum awp = aw (each e-half once); lane-sum z = 2*Z.
        float y = bias[0] + fo + 2.f * awp / z;
        out[smp] = 1.f / (1.f + __expf(-y));
    }
}

extern "C" void kernel_launch(void* const* d_in, const int* in_sizes, int n_in,
                              void* d_out, int out_size, void* d_ws, size_t ws_size,
                              hipStream_t stream) {
    const int*   fidx      = (const int*)  d_in[0];
    const float* fval      = (const float*)d_in[1];
    const float* fow       = (const float*)d_in[2];
    const float* emb_table = (const float*)d_in[3];
    const float* bias      = (const float*)d_in[4];
    const float* attn_w    = (const float*)d_in[5];
    const float* attn_b    = (const float*)d_in[6];
    const float* proj_h    = (const float*)d_in[7];
    const float* proj_p    = (const float*)d_in[8];
    float* out = (float*)d_out;

    afm_kernel<<<BB / 4, 256, 0, stream>>>(fidx, fval, fow, emb_table, bias,
                                           attn_w, attn_b, proj_h, proj_p, out);
}

// Round 12
// 124.481 us; speedup vs baseline: 2.4474x; 1.0177x over previous
//
#include <hip/hip_runtime.h>
#include <hip/hip_fp16.h>
#include <math.h>

// AFM forward, round 12: pooling folded INTO the MFMA via the unused M rows.
// A-row 16 = proj_p, so D[16][n] = bi_n . p = u_n lands in d[8] of h=0 lanes
// (h=1 lanes' d[8] is zero-row 20 -> adds 0). Per tile the entire pooling is
// one fmaf(w, d[8], aw): deletes 4 pk_fma + 1 cvt per tile, the pooled
// register state, and the epilogue dot. First-order reduce merged into the
// final shuffle block. launch_bounds relaxed to (256,5) for +25% occupancy
// (cap 102 VGPR; kernel needs ~90 after the register diet -- r6's spill was
// cap 64 vs need 100, not comparable).
// Structure otherwise r11: zero barriers, constexpr pair table preloaded to
// registers, fp16 rows in LDS, 1-tile-ahead ds_read prefetch,
// mfma_f32_32x32x16_f16, packed relu-dot2 score, exp2 with pre-scaled h.

#define BB 8192
#define FF 39
#define PP 741
#define NT 24                 // 32-pair tiles per sample; tile 23 has 5 valid
#define RBYTES 48             // fp16 row stride: 32B data + 16B pad
#define SBYTES (FF * RBYTES)  // 1872 B per sample

typedef _Float16 f16x8 __attribute__((ext_vector_type(8)));
typedef _Float16 h2    __attribute__((ext_vector_type(2)));
typedef __fp16   hw2   __attribute__((ext_vector_type(2)));  // builtin ABI type
typedef float    f32x4  __attribute__((ext_vector_type(4)));
typedef float    f32x16 __attribute__((ext_vector_type(16)));

// static pair table, transposed: v[n][k] = byte offsets of pair p = k*32+n,
// packed (i*RBYTES)<<16 | (j*RBYTES). Dead slots (p>=741) stay 0 (masked).
struct alignas(16) PijT { unsigned v[32][NT]; };
static constexpr PijT make_pij() {
    PijT t{};
    int p = 0;
    for (int i = 0; i < FF; ++i)
        for (int j = i + 1; j < FF; ++j) {
            t.v[p & 31][p >> 5] =
                ((unsigned)(i * RBYTES) << 16) | (unsigned)(j * RBYTES);
            ++p;
        }
    return t;
}
__device__ constexpr PijT c_pij = make_pij();

static __device__ __forceinline__ h2 cvt2(float lo, float hi) {
    return __builtin_bit_cast(h2, __builtin_amdgcn_cvt_pkrtz(lo, hi));
}
static __device__ __forceinline__ h2 ash2(unsigned d) {
    return __builtin_bit_cast(h2, d);
}
static __device__ __forceinline__ float fdot2f(h2 a, h2 b, float c) {
    return __builtin_amdgcn_fdot2(__builtin_bit_cast(hw2, a),
                                  __builtin_bit_cast(hw2, b), c, false);
}
static __device__ __forceinline__ h2 relu2(h2 x) {
    const h2 zz = {(_Float16)0.f, (_Float16)0.f};
    return __builtin_elementwise_max(x, zz);   // v_pk_max_f16
}

__global__ __launch_bounds__(256, 5)
void afm_kernel(const int*   __restrict__ fidx,
                const float* __restrict__ fval,
                const float* __restrict__ fow,
                const float* __restrict__ emb,
                const float* __restrict__ bias,
                const float* __restrict__ aw_,   // [E=16][A=16] row-major
                const float* __restrict__ ab_,   // [16]
                const float* __restrict__ ph_,   // [16]
                const float* __restrict__ pp_,   // [16]
                float*       __restrict__ out)
{
    __shared__ __align__(16) unsigned char s_emb[4 * SBYTES];  // 7488 B

    const int tid  = threadIdx.x;
    const int wid  = tid >> 6;
    const int lane = tid & 63;
    const int n    = lane & 31;      // pair slot within tile
    const int h    = lane >> 5;      // e-half / k-half
    const int smp  = blockIdx.x * 4 + wid;

    // ---- per-wave: indices + values ----
    int ixr = 0; float vr = 0.f;
    if (lane < FF) {
        ixr = fidx[smp * FF + lane];
        vr  = fval[smp * FF + lane];
    }

    // ---- stage scaled rows as fp16 (78 half-row tasks, same wave) ----
    unsigned char* my = s_emb + wid * SBYTES;
    for (int u = lane; u < FF * 2; u += 64) {
        int row = u >> 1, hh = u & 1;
        int   ix = __shfl(ixr, row);
        float v  = __shfl(vr,  row);
        const float4* src = (const float4*)emb + (size_t)ix * 4 + hh * 2;
        float4 e0 = src[0], e1 = src[1];
        h2 a0 = cvt2(e0.x * v, e0.y * v);
        h2 a1 = cvt2(e0.z * v, e0.w * v);
        h2 a2 = cvt2(e1.x * v, e1.y * v);
        h2 a3 = cvt2(e1.z * v, e1.w * v);
        uint4 d = make_uint4(__builtin_bit_cast(unsigned, a0),
                             __builtin_bit_cast(unsigned, a1),
                             __builtin_bit_cast(unsigned, a2),
                             __builtin_bit_cast(unsigned, a3));
        *(uint4*)(my + row * RBYTES + hh * 16) = d;
    }

    // ---- first-order partial (reduced at the very end with aw,z) ----
    float fo = (lane < FF) ? fow[ixr] * vr : 0.f;

    // ---- constant fragments ----
    const float LOG2E = 1.44269504088896f;
    // packed h coefficients (pre-scaled by log2 e), matching D-reg pair order:
    // regs 0..3 -> a = 4h + r ; regs 4..7 -> a = 8 + 4h + r
    h2 hp0, hp1, hp2, hp3;
    {
        const f32x4 lo = ((const f32x4*)ph_)[h];
        const f32x4 hi = ((const f32x4*)ph_)[h + 2];
        hp0 = cvt2(lo[0] * LOG2E, lo[1] * LOG2E);
        hp1 = cvt2(lo[2] * LOG2E, lo[3] * LOG2E);
        hp2 = cvt2(hi[0] * LOG2E, hi[1] * LOG2E);
        hp3 = cvt2(hi[2] * LOG2E, hi[3] * LOG2E);
    }

    f32x16 cinit;                   // bias in rows a<16; rows >=16 zero
    {                               // (row 16 = proj_p row must have C=0)
        const f32x4 ab_lo = ((const f32x4*)ab_)[h];
        const f32x4 ab_hi = ((const f32x4*)ab_)[h + 2];
        cinit[0] = ab_lo[0]; cinit[1] = ab_lo[1];
        cinit[2] = ab_lo[2]; cinit[3] = ab_lo[3];
        cinit[4] = ab_hi[0]; cinit[5] = ab_hi[1];
        cinit[6] = ab_hi[2]; cinit[7] = ab_hi[3];
        #pragma unroll
        for (int r = 8; r < 16; ++r) cinit[r] = 0.f;
    }

    f16x8 wfrag;        // A: rows 0..15 = W^T, row 16 = proj_p, 17..31 zero
    {
        float t0 = 0.f, t1 = 0.f, t2 = 0.f, t3 = 0.f,
              t4 = 0.f, t5 = 0.f, t6 = 0.f, t7 = 0.f;
        if (n < 16) {
            const float* base = aw_ + (8 * h) * 16 + n;  // W[k=8h+j][m=n]
            t0 = base[0];   t1 = base[16];  t2 = base[32];  t3 = base[48];
            t4 = base[64];  t5 = base[80];  t6 = base[96];  t7 = base[112];
        } else if (n == 16) {
            const float* base = pp_ + 8 * h;             // p[k=8h+j]
            t0 = base[0]; t1 = base[1]; t2 = base[2]; t3 = base[3];
            t4 = base[4]; t5 = base[5]; t6 = base[6]; t7 = base[7];
        }
        union { h2 hh[4]; f16x8 v; } u;
        u.hh[0] = cvt2(t0, t1); u.hh[1] = cvt2(t2, t3);
        u.hh[2] = cvt2(t4, t5); u.hh[3] = cvt2(t6, t7);
        wfrag = u.v;
    }

    // ---- preload all 24 pair offsets into registers (L1, 6 dwordx4) ----
    unsigned po[NT];
    {
        const uint4* myp4 = (const uint4*)c_pij.v[n];
        #pragma unroll
        for (int g = 0; g < 6; ++g) {
            uint4 q = myp4[g];
            po[4 * g + 0] = q.x; po[4 * g + 1] = q.y;
            po[4 * g + 2] = q.z; po[4 * g + 3] = q.w;
        }
    }

    // ---- main loop: 24 tiles, software-pipelined LDS reads (1 tile ahead) --
    const unsigned char* bpre = my + h * 16;    // this lane's e-half
    float aw = 0.f;                             // sum_p w_p * (bi_p . p)
    float z  = 0.f;                             // sum_p w_p (x2 across halves)

    uint4 di = *(const uint4*)(bpre + (po[0] >> 16));
    uint4 dj = *(const uint4*)(bpre + (po[0] & 0xFFFFu));

    #pragma unroll
    for (int t = 0; t < NT; ++t) {
        uint4 diN = di, djN = dj;
        if (t + 1 < NT) {                        // compile-time under unroll
            diN = *(const uint4*)(bpre + (po[t + 1] >> 16));
            djN = *(const uint4*)(bpre + (po[t + 1] & 0xFFFFu));
        }
        h2 m0 = ash2(di.x) * ash2(dj.x);         // v_pk_mul_f16
        h2 m1 = ash2(di.y) * ash2(dj.y);
        h2 m2 = ash2(di.z) * ash2(dj.z);
        h2 m3 = ash2(di.w) * ash2(dj.w);
        union { h2 hh[4]; f16x8 v; } u;
        u.hh[0] = m0; u.hh[1] = m1; u.hh[2] = m2; u.hh[3] = m3;
        f32x16 d = __builtin_amdgcn_mfma_f32_32x32x16_f16(wfrag, u.v,
                                                          cinit, 0, 0, 0);
        h2 c0 = relu2(cvt2(d[0], d[1]));
        h2 c1 = relu2(cvt2(d[2], d[3]));
        h2 c2 = relu2(cvt2(d[4], d[5]));
        h2 c3 = relu2(cvt2(d[6], d[7]));
        float s = fdot2f(c0, hp0,
                  fdot2f(c1, hp1,
                  fdot2f(c2, hp2,
                  fdot2f(c3, hp3, 0.f))));       // v_dot2_f32_f16 x4
        s += __shfl_xor(s, 32);                  // sum the two a-halves
        float w = __builtin_amdgcn_exp2f(s);
        if (t == NT - 1) w = (n < PP - (NT - 1) * 32) ? w : 0.f;
        z  += w;
        aw  = fmaf(w, d[8], aw);   // d[8]: row16 (=bi.p) on h=0, zero on h=1
        di = diN; dj = djN;
    }

    // ---- final reduce: aw, z, fo in one shuffle block ----
    #pragma unroll
    for (int m = 1; m < 64; m <<= 1) {
        aw += __shfl_xor(aw, m);
        z  += __shfl_xor(z, m);
        fo += __shfl_xor(fo, m);
    }
    if (lane == 0) {
        // lane-sum aw counts each pair once; lane-sum z = 2*Z.
        float y = bias[0] + fo + 2.f * aw / z;
        out[smp] = 1.f / (1.f + __expf(-y));
    }
}

extern "C" void kernel_launch(void* const* d_in, const int* in_sizes, int n_in,
                              void* d_out, int out_size, void* d_ws, size_t ws_size,
                              hipStream_t stream) {
    const int*   fidx      = (const int*)  d_in[0];
    const float* fval      = (const float*)d_in[1];
    const float* fow       = (const float*)d_in[2];
    const float* emb_table = (const float*)d_in[3];
    const float* bias      = (const float*)d_in[4];
    const float* attn_w    = (const float*)d_in[5];
    const float* attn_b    = (const float*)d_in[6];
    const float* proj_h    = (const float*)d_in[7];
    const float* proj_p    = (const float*)d_in[8];
    float* out = (float*)d_out;

    afm_kernel<<<BB / 4, 256, 0, stream>>>(fidx, fval, fow, emb_table, bias,
                                           attn_w, attn_b, proj_h, proj_p, out);
}